// Round 1
// baseline (158.313 us; speedup 1.0000x reference)
//
#include <hip/hip_runtime.h>
#include <cstdint>
#include <cstddef>

#define CLS 512
#define NBINS 10
#define SLOTS 64   // histogram slot copies to spread atomic contention

// ws layout: [ uint32 H[SLOTS][NBINS] | double D[SLOTS][NBINS] ]  (~7.7 KB)

__global__ __launch_bounds__(256) void ghm_init_kernel(unsigned int* __restrict__ H,
                                                       double* __restrict__ D) {
    for (int k = threadIdx.x; k < SLOTS * NBINS; k += 256) {
        H[k] = 0u;
        D[k] = 0.0;
    }
}

// One wave (64 lanes) per row; 4 waves per block.
__global__ __launch_bounds__(256) void ghm_main_kernel(const float* __restrict__ pred,
                                                       const int* __restrict__ target,
                                                       unsigned int* __restrict__ H,
                                                       double* __restrict__ D,
                                                       int nrows) {
    const int lane = threadIdx.x & 63;
    const int wid  = threadIdx.x >> 6;
    const int row  = blockIdx.x * 4 + wid;
    if (row >= nrows) return;

    const float4* pr = reinterpret_cast<const float4*>(pred + (size_t)row * CLS);
    float4 va = pr[lane];        // cols 4*lane .. 4*lane+3
    float4 vb = pr[lane + 64];   // cols 256+4*lane .. +3
    float x[8] = {va.x, va.y, va.z, va.w, vb.x, vb.y, vb.z, vb.w};

    // softmax #1: max, sumexp
    float m = x[0];
#pragma unroll
    for (int i = 1; i < 8; ++i) m = fmaxf(m, x[i]);
#pragma unroll
    for (int o = 32; o > 0; o >>= 1) m = fmaxf(m, __shfl_xor(m, o));

    float e[8];
    float s = 0.0f;
#pragma unroll
    for (int i = 0; i < 8; ++i) { e[i] = expf(x[i] - m); s += e[i]; }
#pragma unroll
    for (int o = 32; o > 0; o >>= 1) s += __shfl_xor(s, o);

    float p[8];
#pragma unroll
    for (int i = 0; i < 8; ++i) p[i] = e[i] / s;

    const int t = target[row];

    // g = |p - onehot|, bin = min(int(g*10), 9)
    int bin[8];
#pragma unroll
    for (int i = 0; i < 8; ++i) {
        int col = (i < 4) ? (4 * lane + i) : (256 + 4 * lane + (i - 4));
        float oh = (col == t) ? 1.0f : 0.0f;
        float g = fabsf(p[i] - oh);
        int b = (int)(g * 10.0f);
        bin[i] = (b > 9) ? 9 : b;
    }

    // softmax #2 (log_softmax of p): m2 = max(p) == 1/s exactly (monotone div, e_max==1)
    float m2 = 1.0f / s;
    float s2 = 0.0f;
#pragma unroll
    for (int i = 0; i < 8; ++i) s2 += expf(p[i] - m2);
#pragma unroll
    for (int o = 32; o > 0; o >>= 1) s2 += __shfl_xor(s2, o);

    // p[target]: select element, then broadcast from owning lane
    int half = (t >> 8) & 1;
    int sl   = (t & 255) >> 2;
    int elem = (t & 3) | (half << 2);
    float ca = (elem & 4)
        ? ((elem & 2) ? ((elem & 1) ? p[7] : p[6]) : ((elem & 1) ? p[5] : p[4]))
        : ((elem & 2) ? ((elem & 1) ? p[3] : p[2]) : ((elem & 1) ? p[1] : p[0]));
    float pt = __shfl(ca, sl);

    float ce = logf(s2) - (pt - m2);   // -(log_softmax(p)[t])

    // per-row bin counts via ballot (uniform SGPR results)
    unsigned int cnt[NBINS];
    unsigned int tot = 0;
#pragma unroll
    for (int b = 1; b < NBINS; ++b) {
        unsigned int c = 0;
#pragma unroll
        for (int i = 0; i < 8; ++i)
            c += (unsigned int)__popcll(__ballot(bin[i] == b));
        cnt[b] = c;
        tot += c;
    }
    cnt[0] = (unsigned int)CLS - tot;

    if (lane == 0) {
        const int slot = row & (SLOTS - 1);
        unsigned int* Hs = H + slot * NBINS;
        double*       Ds = D + slot * NBINS;
#pragma unroll
        for (int b = 0; b < NBINS; ++b) {
            unsigned int c = cnt[b];
            if (c) {
                atomicAdd(&Hs[b], c);
                atomicAdd(&Ds[b], (double)ce * (double)c);
            }
        }
    }
}

__global__ __launch_bounds__(64) void ghm_final_kernel(const unsigned int* __restrict__ H,
                                                       const double* __restrict__ D,
                                                       float* __restrict__ out,
                                                       int nrows) {
    const int lane = threadIdx.x;  // 64 threads, one slot each
    unsigned int h[NBINS];
    double d[NBINS];
#pragma unroll
    for (int b = 0; b < NBINS; ++b) {
        h[b] = H[lane * NBINS + b];
        d[b] = D[lane * NBINS + b];
    }
#pragma unroll
    for (int b = 0; b < NBINS; ++b) {
#pragma unroll
        for (int o = 32; o > 0; o >>= 1) {
            h[b] += __shfl_xor(h[b], o);
            d[b] += __shfl_xor(d[b], o);
        }
    }
    if (lane == 0) {
        int nv = 0;
#pragma unroll
        for (int b = 0; b < NBINS; ++b) nv += (h[b] > 0u) ? 1 : 0;
        float nvf = (float)(nv > 0 ? nv : 1);
        float total = (float)nrows * (float)CLS;  // 2^26, exact in f32

        double loss = 0.0;
#pragma unroll
        for (int b = 0; b < NBINS; ++b) {
            if (h[b] > 0u) {
                // Reference accumulates counts by serial f32 (+1.0): saturates at 2^24.
                unsigned int hc = h[b];
                if (hc > 16777216u) hc = 16777216u;
                float cf    = (float)hc;
                float acc   = 0.1f * cf;      // (1 - momentum) rounds to 0.1f in f32
                float denom = nvf * acc;
                float w     = total / denom;
                float w75   = powf(w, 0.75f);
                loss += (double)w75 * d[b];
            }
        }
        out[0] = (float)(loss / ((double)CLS * (double)nrows));
    }
}

extern "C" void kernel_launch(void* const* d_in, const int* in_sizes, int n_in,
                              void* d_out, int out_size, void* d_ws, size_t ws_size,
                              hipStream_t stream) {
    const float* pred   = (const float*)d_in[0];
    const int*   target = (const int*)d_in[1];
    const int    nrows  = in_sizes[1];

    unsigned int* H = (unsigned int*)d_ws;
    double*       D = (double*)((char*)d_ws + SLOTS * NBINS * sizeof(unsigned int));
    float*        out = (float*)d_out;

    hipLaunchKernelGGL(ghm_init_kernel, dim3(1), dim3(256), 0, stream, H, D);
    int blocks = (nrows + 3) / 4;
    hipLaunchKernelGGL(ghm_main_kernel, dim3(blocks), dim3(256), 0, stream,
                       pred, target, H, D, nrows);
    hipLaunchKernelGGL(ghm_final_kernel, dim3(1), dim3(64), 0, stream, H, D, out, nrows);
}

// Round 2
// 147.777 us; speedup vs baseline: 1.0713x; 1.0713x over previous
//
#include <hip/hip_runtime.h>
#include <cstdint>
#include <cstddef>

#define CLS 512
#define NBINS 10
#define ROWS_PER_BLOCK 64      // 4 waves x 16 rows
#define FXSCALE 16777216.0     // 2^24 fixed-point scale for ce*cnt

// ws layout: [ uint32 H[NBINS] | uint64 Dq[NBINS] ]  (120 B)

__global__ __launch_bounds__(64) void ghm_init_kernel(unsigned int* __restrict__ H,
                                                      unsigned long long* __restrict__ Dq) {
    int t = threadIdx.x;
    if (t < NBINS) { H[t] = 0u; Dq[t] = 0ull; }
}

// One wave (64 lanes) per row; block aggregates 64 rows in LDS, then 20 int atomics.
__global__ __launch_bounds__(256) void ghm_main_kernel(const float* __restrict__ pred,
                                                       const int* __restrict__ target,
                                                       unsigned int* __restrict__ H,
                                                       unsigned long long* __restrict__ Dq,
                                                       int nrows) {
    __shared__ unsigned int sH[NBINS];
    __shared__ unsigned long long sD[NBINS];
    if (threadIdx.x < NBINS) { sH[threadIdx.x] = 0u; sD[threadIdx.x] = 0ull; }
    __syncthreads();

    const int lane = threadIdx.x & 63;
    const int wid  = threadIdx.x >> 6;
    const int base = blockIdx.x * ROWS_PER_BLOCK;

    for (int r = wid; r < ROWS_PER_BLOCK; r += 4) {
        const int row = base + r;
        if (row >= nrows) break;

        const float4* pr = reinterpret_cast<const float4*>(pred + (size_t)row * CLS);
        float4 va = pr[lane];        // cols 4*lane .. 4*lane+3
        float4 vb = pr[lane + 64];   // cols 256+4*lane .. +3
        float x[8] = {va.x, va.y, va.z, va.w, vb.x, vb.y, vb.z, vb.w};

        // softmax #1: max, sumexp
        float m = x[0];
#pragma unroll
        for (int i = 1; i < 8; ++i) m = fmaxf(m, x[i]);
#pragma unroll
        for (int o = 32; o > 0; o >>= 1) m = fmaxf(m, __shfl_xor(m, o));

        float e[8];
        float s = 0.0f;
#pragma unroll
        for (int i = 0; i < 8; ++i) { e[i] = __expf(x[i] - m); s += e[i]; }
#pragma unroll
        for (int o = 32; o > 0; o >>= 1) s += __shfl_xor(s, o);

        float p[8];
#pragma unroll
        for (int i = 0; i < 8; ++i) p[i] = e[i] / s;

        const int t = target[row];

        // g = |p - onehot|, bin = min(int(g*10), 9)
        int bin[8];
#pragma unroll
        for (int i = 0; i < 8; ++i) {
            int col = (i < 4) ? (4 * lane + i) : (256 + 4 * lane + (i - 4));
            float oh = (col == t) ? 1.0f : 0.0f;
            float g = fabsf(p[i] - oh);
            int b = (int)(g * 10.0f);
            bin[i] = (b > 9) ? 9 : b;
        }

        // softmax #2 (log_softmax of p): max(p) == 1/s exactly (e_max == 1)
        float m2 = 1.0f / s;
        float s2 = 0.0f;
#pragma unroll
        for (int i = 0; i < 8; ++i) s2 += __expf(p[i] - m2);
#pragma unroll
        for (int o = 32; o > 0; o >>= 1) s2 += __shfl_xor(s2, o);

        // p[target]: select element, broadcast from owning lane
        int half = (t >> 8) & 1;
        int sl   = (t & 255) >> 2;
        int elem = (t & 3) | (half << 2);
        float ca = (elem & 4)
            ? ((elem & 2) ? ((elem & 1) ? p[7] : p[6]) : ((elem & 1) ? p[5] : p[4]))
            : ((elem & 2) ? ((elem & 1) ? p[3] : p[2]) : ((elem & 1) ? p[1] : p[0]));
        float pt = __shfl(ca, sl);

        float ce = __logf(s2) - (pt - m2);   // -(log_softmax(p)[t])

        // per-row bin counts via ballot (wave-uniform results)
        unsigned int cnt[NBINS];
        unsigned int tot = 0;
#pragma unroll
        for (int b = 1; b < NBINS; ++b) {
            unsigned int c = 0;
#pragma unroll
            for (int i = 0; i < 8; ++i)
                c += (unsigned int)__popcll(__ballot(bin[i] == b));
            cnt[b] = c;
            tot += c;
        }
        cnt[0] = (unsigned int)CLS - tot;

        if (lane == 0) {
#pragma unroll
            for (int b = 0; b < NBINS; ++b) {
                unsigned int c = cnt[b];
                if (c) {
                    atomicAdd(&sH[b], c);
                    double contrib = (double)ce * (double)c * FXSCALE;
                    atomicAdd(&sD[b], (unsigned long long)__double2ll_rn(contrib));
                }
            }
        }
    }

    __syncthreads();
    if (threadIdx.x < NBINS) {
        unsigned int hc = sH[threadIdx.x];
        unsigned long long dc = sD[threadIdx.x];
        if (hc) atomicAdd(&H[threadIdx.x], hc);
        if (dc) atomicAdd(&Dq[threadIdx.x], dc);
    }
}

__global__ __launch_bounds__(64) void ghm_final_kernel(const unsigned int* __restrict__ H,
                                                       const unsigned long long* __restrict__ Dq,
                                                       float* __restrict__ out,
                                                       int nrows) {
    if (threadIdx.x != 0) return;

    unsigned int h[NBINS];
    double d[NBINS];
#pragma unroll
    for (int b = 0; b < NBINS; ++b) {
        h[b] = H[b];
        d[b] = (double)Dq[b] * (1.0 / FXSCALE);
    }

    int nv = 0;
#pragma unroll
    for (int b = 0; b < NBINS; ++b) nv += (h[b] > 0u) ? 1 : 0;
    float nvf = (float)(nv > 0 ? nv : 1);
    float total = (float)nrows * (float)CLS;  // 2^26, exact in f32

    double loss = 0.0;
#pragma unroll
    for (int b = 0; b < NBINS; ++b) {
        if (h[b] > 0u) {
            // Reference accumulates counts by serial f32 (+1.0): saturates at 2^24.
            unsigned int hc = h[b];
            if (hc > 16777216u) hc = 16777216u;
            float cf    = (float)hc;
            float acc   = 0.1f * cf;      // (1 - momentum) rounds in f32
            float denom = nvf * acc;
            float w     = total / denom;
            float w75   = powf(w, 0.75f);
            loss += (double)w75 * d[b];
        }
    }
    out[0] = (float)(loss / ((double)CLS * (double)nrows));
}

extern "C" void kernel_launch(void* const* d_in, const int* in_sizes, int n_in,
                              void* d_out, int out_size, void* d_ws, size_t ws_size,
                              hipStream_t stream) {
    const float* pred   = (const float*)d_in[0];
    const int*   target = (const int*)d_in[1];
    const int    nrows  = in_sizes[1];

    unsigned int*       H  = (unsigned int*)d_ws;
    unsigned long long* Dq = (unsigned long long*)((char*)d_ws + 64);  // 8B-aligned
    float*              out = (float*)d_out;

    hipLaunchKernelGGL(ghm_init_kernel, dim3(1), dim3(64), 0, stream, H, Dq);
    int blocks = (nrows + ROWS_PER_BLOCK - 1) / ROWS_PER_BLOCK;
    hipLaunchKernelGGL(ghm_main_kernel, dim3(blocks), dim3(256), 0, stream,
                       pred, target, H, Dq, nrows);
    hipLaunchKernelGGL(ghm_final_kernel, dim3(1), dim3(64), 0, stream, H, Dq, out, nrows);
}

// Round 3
// 93.510 us; speedup vs baseline: 1.6930x; 1.5803x over previous
//
#include <hip/hip_runtime.h>
#include <cstdint>
#include <cstddef>

#define CLS 512
#define NBINS 10
#define ROWS_PER_BLOCK 64      // 4 waves x 16 rows
#define FXSCALE 16777216.0f    // 2^24 fixed-point scale for ce*cnt

// ws layout: [ uint32 H[NBINS] | pad | uint64 Dq[NBINS] ]

__global__ __launch_bounds__(64) void ghm_init_kernel(unsigned int* __restrict__ H,
                                                      unsigned long long* __restrict__ Dq) {
    int t = threadIdx.x;
    if (t < NBINS) { H[t] = 0u; Dq[t] = 0ull; }
}

// One wave per row. Histogram built as packed 4-bit x 9 fields in a u64:
// since sum(p)=1, at most 11 elements/row have g >= 0.1 (10 non-target with
// p>=0.1 plus the target), so every field's wave-wide sum is <= 11 < 16.
__global__ __launch_bounds__(256) void ghm_main_kernel(const float* __restrict__ pred,
                                                       const int* __restrict__ target,
                                                       unsigned int* __restrict__ H,
                                                       unsigned long long* __restrict__ Dq,
                                                       int nrows) {
    __shared__ unsigned int sH[NBINS];
    __shared__ unsigned long long sD[NBINS];
    if (threadIdx.x < NBINS) { sH[threadIdx.x] = 0u; sD[threadIdx.x] = 0ull; }
    __syncthreads();

    const int lane = threadIdx.x & 63;
    const int wid  = threadIdx.x >> 6;
    const int base = blockIdx.x * ROWS_PER_BLOCK;

    for (int r = wid; r < ROWS_PER_BLOCK; r += 4) {
        const int row = base + r;
        if (row >= nrows) break;

        const float4* pr = reinterpret_cast<const float4*>(pred + (size_t)row * CLS);
        float4 va = pr[lane];        // cols 4*lane .. 4*lane+3
        float4 vb = pr[lane + 64];   // cols 256+4*lane .. +3
        float x[8] = {va.x, va.y, va.z, va.w, vb.x, vb.y, vb.z, vb.w};

        // softmax: max, sumexp
        float m = fmaxf(fmaxf(fmaxf(x[0], x[1]), fmaxf(x[2], x[3])),
                        fmaxf(fmaxf(x[4], x[5]), fmaxf(x[6], x[7])));
#pragma unroll
        for (int o = 32; o > 0; o >>= 1) m = fmaxf(m, __shfl_xor(m, o));

        float e[8];
        float s = 0.0f;
#pragma unroll
        for (int i = 0; i < 8; ++i) { e[i] = __expf(x[i] - m); s += e[i]; }
#pragma unroll
        for (int o = 32; o > 0; o >>= 1) s += __shfl_xor(s, o);

        const float inv = __builtin_amdgcn_rcpf(s);   // s >= 1 always

        const int t  = target[row];          // wave-uniform
        const int tl = (t & 255) >> 2;       // owner lane
        const int te = (t & 3) | ((t >> 8) << 2);  // element index 0..7 (uniform)

        // Per-element: p, bin (g=p for non-target), packed hist, Taylor term for
        // s2 = sum_i exp(p_i), and target-prob capture.
        unsigned long long hist = 0ull;
        float s2p = 0.0f;
        float ptv = 0.0f;
#pragma unroll
        for (int i = 0; i < 8; ++i) {
            float pi = e[i] * inv;
            int b = (int)(pi * 10.0f);
            b = (b > 9) ? 9 : b;
            hist += (unsigned long long)(b != 0) << (((b - 1) & 15) << 2);
            // exp(p)-1-p ~= p^2*(1/2 + p/6 + p^2/24)  (quartic Taylor, err<2e-5 on ce)
            float tq = fmaf(pi, 0.0416666679f, 0.166666672f);
            tq = fmaf(pi, tq, 0.5f);
            s2p = fmaf(pi * pi, tq, s2p);
            if (te == i) ptv = pi;
        }
        if (lane != tl) {
            ptv = 0.0f;
        } else {
            // fix the target element: bin from g = 1 - p_t instead of g = p_t
            float pt_ = ptv;
            int bp = (int)(pt_ * 10.0f);          bp = (bp > 9) ? 9 : bp;
            int bt = (int)((1.0f - pt_) * 10.0f); bt = (bt > 9) ? 9 : bt;
            hist -= (unsigned long long)(bp != 0) << (((bp - 1) & 15) << 2);
            hist += (unsigned long long)(bt != 0) << (((bt - 1) & 15) << 2);
        }

        // one combined reduce: hist (u64) + s2 partial + p_t broadcast (3 ILP chains)
#pragma unroll
        for (int o = 32; o > 0; o >>= 1) {
            hist += __shfl_xor(hist, o);
            s2p  += __shfl_xor(s2p, o);
            ptv  += __shfl_xor(ptv, o);
        }

        if (lane == 0) {
            // ce = log(sum exp(p_i)) - p_t ;  sum exp(p_i) ~= 512 + 1 + s2p
            float ce = __logf(513.0f + s2p) - ptv;
            unsigned int total = 0;
            unsigned int c[9];
#pragma unroll
            for (int b = 0; b < 9; ++b) {
                c[b] = (unsigned int)((hist >> (4 * b)) & 15ull);
                total += c[b];
            }
            unsigned int c0 = (unsigned int)CLS - total;
            atomicAdd(&sH[0], c0);
            atomicAdd(&sD[0], (unsigned long long)(long long)(ce * (float)c0 * FXSCALE));
#pragma unroll
            for (int b = 0; b < 9; ++b) {
                unsigned int cb = c[b];
                if (cb) {
                    atomicAdd(&sH[b + 1], cb);
                    atomicAdd(&sD[b + 1], (unsigned long long)(long long)(ce * (float)cb * FXSCALE));
                }
            }
        }
    }

    __syncthreads();
    if (threadIdx.x < NBINS) {
        unsigned int hc = sH[threadIdx.x];
        unsigned long long dc = sD[threadIdx.x];
        if (hc) atomicAdd(&H[threadIdx.x], hc);
        if (dc) atomicAdd(&Dq[threadIdx.x], dc);
    }
}

__global__ __launch_bounds__(64) void ghm_final_kernel(const unsigned int* __restrict__ H,
                                                       const unsigned long long* __restrict__ Dq,
                                                       float* __restrict__ out,
                                                       int nrows) {
    if (threadIdx.x != 0) return;

    unsigned int h[NBINS];
    double d[NBINS];
#pragma unroll
    for (int b = 0; b < NBINS; ++b) {
        h[b] = H[b];
        d[b] = (double)Dq[b] * (1.0 / 16777216.0);
    }

    int nv = 0;
#pragma unroll
    for (int b = 0; b < NBINS; ++b) nv += (h[b] > 0u) ? 1 : 0;
    float nvf = (float)(nv > 0 ? nv : 1);
    float total = (float)nrows * (float)CLS;  // 2^26, exact in f32

    double loss = 0.0;
#pragma unroll
    for (int b = 0; b < NBINS; ++b) {
        if (h[b] > 0u) {
            // Reference accumulates counts by serial f32 (+1.0): saturates at 2^24.
            unsigned int hc = h[b];
            if (hc > 16777216u) hc = 16777216u;
            float cf    = (float)hc;
            float acc   = 0.1f * cf;      // (1 - momentum) in f32
            float denom = nvf * acc;
            float w     = total / denom;
            float w75   = powf(w, 0.75f);
            loss += (double)w75 * d[b];
        }
    }
    out[0] = (float)(loss / ((double)CLS * (double)nrows));
}

extern "C" void kernel_launch(void* const* d_in, const int* in_sizes, int n_in,
                              void* d_out, int out_size, void* d_ws, size_t ws_size,
                              hipStream_t stream) {
    const float* pred   = (const float*)d_in[0];
    const int*   target = (const int*)d_in[1];
    const int    nrows  = in_sizes[1];

    unsigned int*       H  = (unsigned int*)d_ws;
    unsigned long long* Dq = (unsigned long long*)((char*)d_ws + 64);  // 8B-aligned
    float*              out = (float*)d_out;

    hipLaunchKernelGGL(ghm_init_kernel, dim3(1), dim3(64), 0, stream, H, Dq);
    int blocks = (nrows + ROWS_PER_BLOCK - 1) / ROWS_PER_BLOCK;
    hipLaunchKernelGGL(ghm_main_kernel, dim3(blocks), dim3(256), 0, stream,
                       pred, target, H, Dq, nrows);
    hipLaunchKernelGGL(ghm_final_kernel, dim3(1), dim3(64), 0, stream, H, Dq, out, nrows);
}

// Round 4
// 76.012 us; speedup vs baseline: 2.0827x; 1.2302x over previous
//
#include <hip/hip_runtime.h>
#include <cstdint>
#include <cstddef>

#define CLS 512
#define NBINS 10
#define ROWS_PER_BLOCK 64      // 4 waves x 16 rows
#define FXSCALE 16777216.0f    // 2^24 fixed-point scale for ce*cnt
#define LOG513 6.2402782f      // ln(513); fast-path log(sum exp(p)) to ~1e-5

// ws layout: [ uint32 H[NBINS] | pad to 64B | uint64 Dq[NBINS] ]

__global__ __launch_bounds__(64) void ghm_init_kernel(unsigned int* __restrict__ H,
                                                      unsigned long long* __restrict__ Dq) {
    int t = threadIdx.x;
    if (t < NBINS) { H[t] = 0u; Dq[t] = 0ull; }
}

// One wave per row; 16 rows per wave with next-row prefetch.
// Fast path: e_max == 1 exactly, so p_max == 1/s. If s > 10 then every
// non-target p < 0.1 (bin 0) and target g = 1-p_t > 0.9 (bin 9), and
// log(sum_i exp(p_i)) == ln(513) + [0, 1.1e-5]. Covers ~all rows for
// N(0,1) logits; exact packed-hist slow path kept for s <= 10.
__global__ __launch_bounds__(256) void ghm_main_kernel(const float* __restrict__ pred,
                                                       const int* __restrict__ target,
                                                       unsigned int* __restrict__ H,
                                                       unsigned long long* __restrict__ Dq,
                                                       int nrows) {
    __shared__ unsigned int sH[NBINS];
    __shared__ unsigned long long sD[NBINS];
    if (threadIdx.x < NBINS) { sH[threadIdx.x] = 0u; sD[threadIdx.x] = 0ull; }
    __syncthreads();

    const int lane = threadIdx.x & 63;
    const int wid  = threadIdx.x >> 6;
    const int base = blockIdx.x * ROWS_PER_BLOCK;

    // per-wave fast-path accumulators (flushed once at the end)
    unsigned int c0a = 0u, c9a = 0u;
    float d0a = 0.0f, d9a = 0.0f;

    // prefetch first row
    float4 va = make_float4(0.f, 0.f, 0.f, 0.f), vb = va;
    if (base + wid < nrows) {
        const float4* pr = reinterpret_cast<const float4*>(pred + (size_t)(base + wid) * CLS);
        va = pr[lane];
        vb = pr[lane + 64];
    }

    for (int rr = wid; rr < ROWS_PER_BLOCK; rr += 4) {
        const int row = base + rr;
        if (row >= nrows) break;

        // issue next row's loads before computing on the current one
        float4 nva = make_float4(0.f, 0.f, 0.f, 0.f), nvb = nva;
        const int nxt = rr + 4;
        if (nxt < ROWS_PER_BLOCK && base + nxt < nrows) {
            const float4* pn = reinterpret_cast<const float4*>(pred + (size_t)(base + nxt) * CLS);
            nva = pn[lane];
            nvb = pn[lane + 64];
        }

        float x[8] = {va.x, va.y, va.z, va.w, vb.x, vb.y, vb.z, vb.w};

        // softmax: max-reduce, exp, sum-reduce
        float m = fmaxf(fmaxf(fmaxf(x[0], x[1]), fmaxf(x[2], x[3])),
                        fmaxf(fmaxf(x[4], x[5]), fmaxf(x[6], x[7])));
#pragma unroll
        for (int o = 32; o > 0; o >>= 1) m = fmaxf(m, __shfl_xor(m, o));

        float e[8];
        float s = 0.0f;
#pragma unroll
        for (int i = 0; i < 8; ++i) { e[i] = __expf(x[i] - m); s += e[i]; }
#pragma unroll
        for (int o = 32; o > 0; o >>= 1) s += __shfl_xor(s, o);

        const float inv = __builtin_amdgcn_rcpf(s);   // s >= 1 always

        const int t  = target[row];                 // wave-uniform
        const int tl = (t & 255) >> 2;              // owner lane
        const int te = (t & 3) | ((t >> 8) << 2);   // element index 0..7 (uniform)

        // p_t: select target element of e (uniform index), broadcast, scale
        float ca = (te & 4)
            ? ((te & 2) ? ((te & 1) ? e[7] : e[6]) : ((te & 1) ? e[5] : e[4]))
            : ((te & 2) ? ((te & 1) ? e[3] : e[2]) : ((te & 1) ? e[1] : e[0]));
        const float ptv = __shfl(ca, tl) * inv;     // wave-uniform p_target

        if (s > 10.0f) {
            // ---- fast path: bins {0: 511, 9: 1} ----
            float ce = LOG513 - ptv;
            c0a += 511u;
            c9a += 1u;
            d0a = fmaf(ce, 511.0f, d0a);
            d9a += ce;
        } else {
            // ---- exact slow path: packed 4-bit x 9 hist + Taylor for s2 ----
            unsigned long long hist = 0ull;
            float s2p = 0.0f;
#pragma unroll
            for (int i = 0; i < 8; ++i) {
                float pi = e[i] * inv;
                int b = (int)(pi * 10.0f);
                b = (b > 9) ? 9 : b;
                int isT = (lane == tl) & (i == te);
                hist += (unsigned long long)((b != 0) & !isT) << (((b - 1) & 15) << 2);
                // exp(p)-1-p ~= p^2*(1/2 + p/6 + p^2/24)
                float tq = fmaf(pi, 0.0416666679f, 0.166666672f);
                tq = fmaf(pi, tq, 0.5f);
                s2p = fmaf(pi * pi, tq, s2p);
            }
            if (lane == tl) {
                int bt = (int)((1.0f - ptv) * 10.0f);
                bt = (bt > 9) ? 9 : bt;
                hist += (unsigned long long)(bt != 0) << (((bt - 1) & 15) << 2);
            }
#pragma unroll
            for (int o = 32; o > 0; o >>= 1) {
                hist += __shfl_xor(hist, o);
                s2p  += __shfl_xor(s2p, o);
            }
            if (lane == 0) {
                float ce = __logf(513.0f + s2p) - ptv;
                unsigned int total = 0;
                unsigned int c[9];
#pragma unroll
                for (int b = 0; b < 9; ++b) {
                    c[b] = (unsigned int)((hist >> (4 * b)) & 15ull);
                    total += c[b];
                }
                unsigned int c0 = (unsigned int)CLS - total;
                atomicAdd(&sH[0], c0);
                atomicAdd(&sD[0], (unsigned long long)(long long)(ce * (float)c0 * FXSCALE));
#pragma unroll
                for (int b = 0; b < 9; ++b) {
                    unsigned int cb = c[b];
                    if (cb) {
                        atomicAdd(&sH[b + 1], cb);
                        atomicAdd(&sD[b + 1], (unsigned long long)(long long)(ce * (float)cb * FXSCALE));
                    }
                }
            }
        }

        va = nva;
        vb = nvb;
    }

    // flush per-wave fast-path accumulators
    if (lane == 0 && c0a) {
        atomicAdd(&sH[0], c0a);
        atomicAdd(&sH[9], c9a);
        atomicAdd(&sD[0], (unsigned long long)(long long)(d0a * FXSCALE));
        atomicAdd(&sD[9], (unsigned long long)(long long)(d9a * FXSCALE));
    }

    __syncthreads();
    if (threadIdx.x < NBINS) {
        unsigned int hc = sH[threadIdx.x];
        unsigned long long dc = sD[threadIdx.x];
        if (hc) atomicAdd(&H[threadIdx.x], hc);
        if (dc) atomicAdd(&Dq[threadIdx.x], dc);
    }
}

__global__ __launch_bounds__(64) void ghm_final_kernel(const unsigned int* __restrict__ H,
                                                       const unsigned long long* __restrict__ Dq,
                                                       float* __restrict__ out,
                                                       int nrows) {
    if (threadIdx.x != 0) return;

    unsigned int h[NBINS];
    double d[NBINS];
#pragma unroll
    for (int b = 0; b < NBINS; ++b) {
        h[b] = H[b];
        d[b] = (double)Dq[b] * (1.0 / 16777216.0);
    }

    int nv = 0;
#pragma unroll
    for (int b = 0; b < NBINS; ++b) nv += (h[b] > 0u) ? 1 : 0;
    float nvf = (float)(nv > 0 ? nv : 1);
    float total = (float)nrows * (float)CLS;  // 2^26, exact in f32

    double loss = 0.0;
#pragma unroll
    for (int b = 0; b < NBINS; ++b) {
        if (h[b] > 0u) {
            // Reference accumulates counts by serial f32 (+1.0): saturates at 2^24.
            unsigned int hc = h[b];
            if (hc > 16777216u) hc = 16777216u;
            float cf    = (float)hc;
            float acc   = 0.1f * cf;      // (1 - momentum) in f32
            float denom = nvf * acc;
            float w     = total / denom;
            float w75   = powf(w, 0.75f);
            loss += (double)w75 * d[b];
        }
    }
    out[0] = (float)(loss / ((double)CLS * (double)nrows));
}

extern "C" void kernel_launch(void* const* d_in, const int* in_sizes, int n_in,
                              void* d_out, int out_size, void* d_ws, size_t ws_size,
                              hipStream_t stream) {
    const float* pred   = (const float*)d_in[0];
    const int*   target = (const int*)d_in[1];
    const int    nrows  = in_sizes[1];

    unsigned int*       H  = (unsigned int*)d_ws;
    unsigned long long* Dq = (unsigned long long*)((char*)d_ws + 64);  // 8B-aligned
    float*              out = (float*)d_out;

    hipLaunchKernelGGL(ghm_init_kernel, dim3(1), dim3(64), 0, stream, H, Dq);
    int blocks = (nrows + ROWS_PER_BLOCK - 1) / ROWS_PER_BLOCK;
    hipLaunchKernelGGL(ghm_main_kernel, dim3(blocks), dim3(256), 0, stream,
                       pred, target, H, Dq, nrows);
    hipLaunchKernelGGL(ghm_final_kernel, dim3(1), dim3(64), 0, stream, H, Dq, out, nrows);
}